// Round 15
// baseline (83.118 us; speedup 1.0000x reference)
//
#include <hip/hip_runtime.h>
#include <hip/hip_bf16.h>

// MMD loss: source/target 4096x256 fp32, output scalar fp32. N=8192, D=256.
// R15: occupancy-first k_mmd. R4-R14 law: dur x resident-waves ~ const
// (latency-bound); occupancy was register-capped at 3 waves/SIMD by the
// 64-AGPR acc[4][4] + 68 VGPR = 132 unified regs. Fix: 32x32x16 MFMA, ONE
// 32x32 tile per wave (16 acc regs), 64x64 pair-tiles (8256 blocks x 4
// waves), KC=32 double-buffer = 16.6 KB LDS, __launch_bounds__(256,6).
// Same proven chunk skeleton (own vmcnt(0) + s_barrier + stage-next).
//
// ws layout (bytes):
//   0      : double slots[8256]          -> 66048
//   66048  : double neg_gamma2           -> 66056
//   66056  : double sqpart[128]          -> 67080
//   67080  : float  cspart[128*256]      -> 198152
//   198152 : float  sq[8192]             -> 230920
//   230928 : bf16   G[8192*256]          -> 4425232
#define WS_SLOT_OFF   0
#define WS_NEGG_OFF   66048
#define WS_SQPART_OFF 66056
#define WS_CSPART_OFF 67080
#define WS_SQ_OFF     198152
#define WS_G_OFF      230928

#define NROW 8192
#define HALF 4096
#define DIM  256
#define TT   64                      // pair-tile size
#define NT   128                     // 8192/64 row-tiles
#define NPAIR (NT * (NT + 1) / 2)    // 8256 upper-tri pairs (= grid)
#define KC   32                      // k-chunk (64 B/row)
#define NC   (DIM / KC)              // 8 chunks
#define BUFE (TT * KC)               // 2048 ushorts / buffer (4 KB)
#define PREPB 128                    // k_prep blocks (64 rows each)

typedef short  short8 __attribute__((ext_vector_type(8)));
typedef float  f32x16 __attribute__((ext_vector_type(16)));
typedef unsigned short us4 __attribute__((ext_vector_type(4)));

static __device__ __forceinline__ unsigned short f2bfbits(float f) {
    __hip_bfloat16 h = __float2bfloat16(f);   // RNE
    return *reinterpret_cast<unsigned short*>(&h);
}
static __device__ __forceinline__ float bfbits2f(unsigned short u) {
    return __uint_as_float(((unsigned int)u) << 16);
}
static __device__ __forceinline__ void gl_lds16(const void* g, void* l) {
    __builtin_amdgcn_global_load_lds(
        (const __attribute__((address_space(1))) void*)g,
        (__attribute__((address_space(3))) void*)l, 16, 0, 0);
}

// ---------- kernel A: cvt + row-sq + per-block colsum/sqsum partials ----------
// 128 blocks x 256 threads; block handles 64 rows; wave w rows r0+w+4i, i<16.
__global__ __launch_bounds__(256) void k_prep(const float* __restrict__ src,
                                              const float* __restrict__ tgt,
                                              unsigned short* __restrict__ G,
                                              float* __restrict__ sq,
                                              float* __restrict__ cspart,
                                              double* __restrict__ sqpart) {
    __shared__ float cs_lds[4 * 256];
    __shared__ double sq_lds[4];

    int t = threadIdx.x, wid = t >> 6, lane = t & 63;
    int r0 = blockIdx.x * 64;
    int c4 = lane * 4;

    float cs0 = 0.f, cs1 = 0.f, cs2 = 0.f, cs3 = 0.f;
    double wsq = 0.0;
    for (int i = 0; i < 16; ++i) {
        int row = r0 + wid + i * 4;
        const float* base = (row < HALF) ? (src + (size_t)row * DIM)
                                         : (tgt + (size_t)(row - HALF) * DIM);
        float4 v = *(const float4*)(base + c4);
        unsigned short u0 = f2bfbits(v.x), u1 = f2bfbits(v.y),
                       u2 = f2bfbits(v.z), u3 = f2bfbits(v.w);
        us4 uu = {u0, u1, u2, u3};
        *(us4*)(G + (size_t)row * DIM + c4) = uu;   // linear, coalesced
        float r0f = bfbits2f(u0), r1f = bfbits2f(u1),
              r2f = bfbits2f(u2), r3f = bfbits2f(u3);
        cs0 += r0f; cs1 += r1f; cs2 += r2f; cs3 += r3f;
        float s = r0f * r0f + r1f * r1f + r2f * r2f + r3f * r3f;
        #pragma unroll
        for (int off = 32; off; off >>= 1) s += __shfl_down(s, off);
        if (lane == 0) { sq[row] = s; wsq += (double)s; }
    }
    cs_lds[wid * 256 + c4 + 0] = cs0;
    cs_lds[wid * 256 + c4 + 1] = cs1;
    cs_lds[wid * 256 + c4 + 2] = cs2;
    cs_lds[wid * 256 + c4 + 3] = cs3;
    if (lane == 0) sq_lds[wid] = wsq;
    __syncthreads();
    float s = cs_lds[t] + cs_lds[256 + t] + cs_lds[512 + t] + cs_lds[768 + t];
    cspart[blockIdx.x * 256 + t] = s;
    if (t == 0)
        sqpart[blockIdx.x] = sq_lds[0] + sq_lds[1] + sq_lds[2] + sq_lds[3];
}

// ---------- kernel B: bandwidth -> neg_gamma2 = -log2(e)/(16*bw) ----------
__global__ __launch_bounds__(256) void k_bw(const float* __restrict__ cspart,
                                            const double* __restrict__ sqpart,
                                            double* __restrict__ negg) {
    __shared__ double red[256];
    __shared__ double red2[256];
    int t = threadIdx.x;
    double c = 0.0;
    for (int b = 0; b < PREPB; ++b) c += (double)cspart[b * 256 + t];
    double s = (t < PREPB) ? sqpart[t] : 0.0;
    red[t]  = s;
    red2[t] = c * c;
    __syncthreads();
    for (int off = 128; off; off >>= 1) {
        if (t < off) { red[t] += red[t + off]; red2[t] += red2[t + off]; }
        __syncthreads();
    }
    if (t == 0) {
        const double N = (double)NROW;
        double sum_l2 = 2.0 * N * red[0] - 2.0 * red2[0];
        double bw = sum_l2 / (N * N - N);
        bw = bw / 4.0;  // KERNEL_MUL ** (KERNEL_NUM//2) = 2^2
        negg[0] = -1.4426950408889634 / (16.0 * bw);  // exp2 scaling
    }
}

// ---------- kernel D: 64x64 pair-tiles, one 32x32 MFMA tile per wave ----------
// LDS [row][k] bf16, KC=32 = 4 slots of 16 B per row. Physical slot p at row
// r holds logical p ^ ((r>>1)&3) (XOR involution; achieves the structural
// minimum LDS transfer for b128 frag reads AND keeps gl_lds dest linear with
// a pre-swizzled source).
__global__ __launch_bounds__(256, 6) void k_mmd(const unsigned short* __restrict__ G,
                                                const float* __restrict__ sq,
                                                const double* __restrict__ negg,
                                                double* __restrict__ slots) {
    __shared__ unsigned short As[2 * BUFE];   // 8 KB
    __shared__ unsigned short Bs[2 * BUFE];   // 8 KB
    __shared__ double wsum[4];

    int bid = blockIdx.x;
    int p = (bid & 7) * (NPAIR / 8) + (bid >> 3);   // XCD-chunked, bijective

    // triangular decode (wave-uniform)
    int ti = 0, rem = p;
    while (rem >= NT - ti) { rem -= NT - ti; ++ti; }
    int tj = ti + rem;

    int t = threadIdx.x, wid = t >> 6, lane = t & 63;
    int wr = wid >> 1, wc = wid & 1;

    const unsigned short* Abase = G + (size_t)ti * TT * DIM;
    const unsigned short* Bbase = G + (size_t)tj * TT * DIM;

    // staging: wave w stages rows [w*16, w*16+16) of A and B (1 KB each).
    // gl_lds dest = base + lane*16: row = w*16 + (l>>2), phys slot = l&3.
    // source slot = (l&3) ^ ((row>>1)&3) = (l&3) ^ ((l>>3)&3)  (w*8 % 4 == 0)
    int sslot = (lane & 3) ^ ((lane >> 3) & 3);
    size_t gsrc = (size_t)(wid * 16 + (lane >> 2)) * DIM + sslot * 8;
    int ldst = (wid * 16) * KC;

    // frag-read offsets: mfma_32x32x16 A-frag: lane l -> row (l&31),
    // k-elems (l>>5)*8; k-slice m uses logical slots {2m, 2m+1}.
    int ra = wr * 32 + (lane & 31);
    int rb = wc * 32 + (lane & 31);
    int sA = lane >> 5;
    int swa = (ra >> 1) & 3, swb = (rb >> 1) & 3;
    int aoff0 = ra * KC + ((sA ^ swa) * 8);
    int aoff1 = ra * KC + (((2 + sA) ^ swa) * 8);
    int boff0 = rb * KC + ((sA ^ swb) * 8);
    int boff1 = rb * KC + (((2 + sA) ^ swb) * 8);

    f32x16 acc = {0.f, 0.f, 0.f, 0.f, 0.f, 0.f, 0.f, 0.f,
                  0.f, 0.f, 0.f, 0.f, 0.f, 0.f, 0.f, 0.f};

    #define STAGE(kc, b)                                                   \
        do {                                                               \
            gl_lds16(Abase + gsrc + (kc) * KC, &As[(b) * BUFE + ldst]);    \
            gl_lds16(Bbase + gsrc + (kc) * KC, &Bs[(b) * BUFE + ldst]);    \
        } while (0)

    STAGE(0, 0);
    #pragma unroll
    for (int kc = 0; kc < NC; ++kc) {
        asm volatile("s_waitcnt vmcnt(0)" ::: "memory");  // my 2 loads done
        __builtin_amdgcn_s_barrier();                      // everyone's done
        __builtin_amdgcn_sched_barrier(0);
        if (kc + 1 < NC) STAGE(kc + 1, (kc + 1) & 1);

        const unsigned short* Ab = &As[(kc & 1) * BUFE];
        const unsigned short* Bb = &Bs[(kc & 1) * BUFE];
        short8 a0 = *(const short8*)&Ab[aoff0];
        short8 b0 = *(const short8*)&Bb[boff0];
        short8 a1 = *(const short8*)&Ab[aoff1];
        short8 b1 = *(const short8*)&Bb[boff1];
        acc = __builtin_amdgcn_mfma_f32_32x32x16_bf16(a0, b0, acc, 0, 0, 0);
        acc = __builtin_amdgcn_mfma_f32_32x32x16_bf16(a1, b1, acc, 0, 0, 0);
    }
    #undef STAGE

    // ---- epilogue: exp2-squaring chain ----
    // C/D 32x32 layout (m74/m101): col = lane&31,
    // row = (q&3) + 8*(q>>2) + 4*(lane>>5), q = acc reg index
    int gi0 = ti * TT + wr * 32 + 4 * (lane >> 5);
    int gj  = tj * TT + wc * 32 + (lane & 31);
    float ng2 = (float)negg[0];               // negative
    float m2g = -2.0f * ng2;                  // positive
    float sqb = sq[gj] * ng2;

    float tsum = 0.f;
    #pragma unroll
    for (int q = 0; q < 16; ++q) {
        int row = (q & 3) + 8 * (q >> 2);
        float sqa = sq[gi0 + row] * ng2;
        float x   = fmaf(acc[q], m2g, sqa + sqb);
        float e   = exp2f(x);
        float e2  = e * e;
        float e4  = e2 * e2;
        float e8  = e4 * e4;
        float e16 = e8 * e8;
        tsum += (e + e2) + (e4 + e8) + e16;
    }

    float w = ((ti < NT / 2) == (tj < NT / 2)) ? 1.f : -1.f;
    if (ti != tj) w *= 2.f;   // off-diagonal tiles count twice (symmetry)
    double dsum = (double)(tsum * w);

    #pragma unroll
    for (int off = 32; off; off >>= 1) dsum += __shfl_down(dsum, off);
    if (lane == 0) wsum[wid] = dsum;
    __syncthreads();
    if (t == 0)
        slots[bid] = wsum[0] + wsum[1] + wsum[2] + wsum[3];  // plain store
}

// ---------- kernel E: finalize (reduce 8256 slots) ----------
__global__ __launch_bounds__(256) void k_final(const double* __restrict__ slots,
                                               float* __restrict__ out) {
    __shared__ double red[256];
    int t = threadIdx.x;
    double s = 0.0;
    for (int i = t; i < NPAIR; i += 256) s += slots[i];
    red[t] = s;
    __syncthreads();
    for (int off = 128; off; off >>= 1) {
        if (t < off) red[t] += red[t + off];
        __syncthreads();
    }
    if (t == 0)
        out[0] = (float)(red[0] / ((double)HALF * (double)HALF));
}

extern "C" void kernel_launch(void* const* d_in, const int* in_sizes, int n_in,
                              void* d_out, int out_size, void* d_ws, size_t ws_size,
                              hipStream_t stream) {
    const float* src = (const float*)d_in[0];
    const float* tgt = (const float*)d_in[1];
    float* out = (float*)d_out;

    double* slots     = (double*)((char*)d_ws + WS_SLOT_OFF);
    double* negg      = (double*)((char*)d_ws + WS_NEGG_OFF);
    double* sqpart    = (double*)((char*)d_ws + WS_SQPART_OFF);
    float*  cspart    = (float*)((char*)d_ws + WS_CSPART_OFF);
    float*  sq        = (float*)((char*)d_ws + WS_SQ_OFF);
    unsigned short* G = (unsigned short*)((char*)d_ws + WS_G_OFF);

    k_prep<<<PREPB, 256, 0, stream>>>(src, tgt, G, sq, cspart, sqpart);
    k_bw<<<1, 256, 0, stream>>>(cspart, sqpart, negg);
    k_mmd<<<NPAIR, 256, 0, stream>>>(G, sq, negg, slots);
    k_final<<<1, 256, 0, stream>>>(slots, out);
}

// Round 16
// 70.164 us; speedup vs baseline: 1.1846x; 1.1846x over previous
//
#include <hip/hip_runtime.h>
#include <hip/hip_bf16.h>

// MMD loss: source/target 4096x256 fp32, output scalar fp32. N=8192, D=256.
// R16: FAT-ROUND k_mmd. R14 diagnosis: 65 rounds/CU x 1650cyc, only ~770cyc
// real work -> ~900cyc/round sync stall (m233's 2-phase overhead). R15 showed
// more occupancy does NOT help. Fix: amortize the stall — 256x256 pair-tiles,
// 8 waves (2x4, 128x64 sub-tile each, acc[8][4]), BK=32 dbuf (64KB LDS),
// SAME proven R14 round skeleton + verified XOR swizzle. 528 pairs total,
// 176 blocks x exactly 3 pairs (perfect balance; consecutive pairs share the
// A row-tile -> L2 reuse).
//
// ws layout (bytes):
//   0      : double slots[176]           -> 1408
//   1408   : double neg_gamma2           -> 1416
//   1416   : double sqpart[256]          -> 3464
//   3464   : float  cspart[256*256]      -> 265608
//   265608 : float  sq[8192]             -> 298376
//   298384 : bf16   G[8192*256]          -> 4492688
#define WS_SLOT_OFF   0
#define WS_NEGG_OFF   1408
#define WS_SQPART_OFF 1416
#define WS_CSPART_OFF 3464
#define WS_SQ_OFF     265608
#define WS_G_OFF      298384

#define NROW 8192
#define HALF 4096
#define DIM  256
#define TS   256                     // pair-tile size
#define NTT  32                      // 8192/256 row-tiles
#define NP   (NTT * (NTT + 1) / 2)   // 528 upper-tri pairs
#define GRID_MMD (NP / 3)            // 176 blocks x 3 pairs
#define KC   32                      // k-chunk (64 B/row)
#define NC   (DIM / KC)              // 8 chunks
#define ABUF (TS * KC)               // 8192 ushorts = 16 KB per buffer
#define PREPB 256                    // k_prep blocks (32 rows each)

typedef short  short8 __attribute__((ext_vector_type(8)));
typedef float  f32x4  __attribute__((ext_vector_type(4)));
typedef float  f32x2  __attribute__((ext_vector_type(2)));
typedef unsigned short us4 __attribute__((ext_vector_type(4)));

static __device__ __forceinline__ unsigned short f2bfbits(float f) {
    __hip_bfloat16 h = __float2bfloat16(f);   // RNE
    return *reinterpret_cast<unsigned short*>(&h);
}
static __device__ __forceinline__ float bfbits2f(unsigned short u) {
    return __uint_as_float(((unsigned int)u) << 16);
}
static __device__ __forceinline__ void gl_lds16(const void* g, void* l) {
    __builtin_amdgcn_global_load_lds(
        (const __attribute__((address_space(1))) void*)g,
        (__attribute__((address_space(3))) void*)l, 16, 0, 0);
}

// ---------- kernel A: cvt + row-sq + per-block colsum/sqsum partials ----------
// 256 blocks x 256 threads; block handles 32 rows; wave w rows r0+w+4i, i<8.
__global__ __launch_bounds__(256) void k_prep(const float* __restrict__ src,
                                              const float* __restrict__ tgt,
                                              unsigned short* __restrict__ G,
                                              float* __restrict__ sq,
                                              float* __restrict__ cspart,
                                              double* __restrict__ sqpart) {
    __shared__ float cs_lds[4 * 256];
    __shared__ double sq_lds[4];

    int t = threadIdx.x, wid = t >> 6, lane = t & 63;
    int r0 = blockIdx.x * 32;
    int c4 = lane * 4;

    float cs0 = 0.f, cs1 = 0.f, cs2 = 0.f, cs3 = 0.f;
    double wsq = 0.0;
    for (int i = 0; i < 8; ++i) {
        int row = r0 + wid + i * 4;
        const float* base = (row < HALF) ? (src + (size_t)row * DIM)
                                         : (tgt + (size_t)(row - HALF) * DIM);
        float4 v = *(const float4*)(base + c4);
        unsigned short u0 = f2bfbits(v.x), u1 = f2bfbits(v.y),
                       u2 = f2bfbits(v.z), u3 = f2bfbits(v.w);
        us4 uu = {u0, u1, u2, u3};
        *(us4*)(G + (size_t)row * DIM + c4) = uu;   // linear, coalesced
        float r0f = bfbits2f(u0), r1f = bfbits2f(u1),
              r2f = bfbits2f(u2), r3f = bfbits2f(u3);
        cs0 += r0f; cs1 += r1f; cs2 += r2f; cs3 += r3f;
        float s = r0f * r0f + r1f * r1f + r2f * r2f + r3f * r3f;
        #pragma unroll
        for (int off = 32; off; off >>= 1) s += __shfl_down(s, off);
        if (lane == 0) { sq[row] = s; wsq += (double)s; }
    }
    cs_lds[wid * 256 + c4 + 0] = cs0;
    cs_lds[wid * 256 + c4 + 1] = cs1;
    cs_lds[wid * 256 + c4 + 2] = cs2;
    cs_lds[wid * 256 + c4 + 3] = cs3;
    if (lane == 0) sq_lds[wid] = wsq;
    __syncthreads();
    float s = cs_lds[t] + cs_lds[256 + t] + cs_lds[512 + t] + cs_lds[768 + t];
    cspart[blockIdx.x * 256 + t] = s;
    if (t == 0)
        sqpart[blockIdx.x] = sq_lds[0] + sq_lds[1] + sq_lds[2] + sq_lds[3];
}

// ---------- kernel B: bandwidth -> neg_gamma2 = -log2(e)/(16*bw) ----------
__global__ __launch_bounds__(256) void k_bw(const float* __restrict__ cspart,
                                            const double* __restrict__ sqpart,
                                            double* __restrict__ negg) {
    __shared__ double red[256];
    __shared__ double red2[256];
    int t = threadIdx.x;
    double c = 0.0;
    for (int b = 0; b < PREPB; ++b) c += (double)cspart[b * 256 + t];
    double s = sqpart[t];
    red[t]  = s;
    red2[t] = c * c;
    __syncthreads();
    for (int off = 128; off; off >>= 1) {
        if (t < off) { red[t] += red[t + off]; red2[t] += red2[t + off]; }
        __syncthreads();
    }
    if (t == 0) {
        const double N = (double)NROW;
        double sum_l2 = 2.0 * N * red[0] - 2.0 * red2[0];
        double bw = sum_l2 / (N * N - N);
        bw = bw / 4.0;  // KERNEL_MUL ** (KERNEL_NUM//2) = 2^2
        negg[0] = -1.4426950408889634 / (16.0 * bw);  // exp2 scaling
    }
}

// ---------- kernel D: 256x256 pair-tiles, 8 waves, fat rounds ----------
// LDS [row][k] bf16, KC=32 (4 slots of 16 B). Physical slot p at row r holds
// logical slot p ^ ((r>>1)&3) — the R14-verified involution (0 conflicts):
// 2-way-max banks on b128 frag reads, linear gl_lds dest w/ pre-swizzled src.
__global__ __launch_bounds__(512, 2) void k_mmd(const unsigned short* __restrict__ G,
                                                const float* __restrict__ sq,
                                                const double* __restrict__ negg,
                                                double* __restrict__ slots) {
    __shared__ unsigned short As[2 * ABUF];   // 32 KB
    __shared__ unsigned short Bs[2 * ABUF];   // 32 KB
    __shared__ double wsum[8];

    int bid = blockIdx.x;
    int t = threadIdx.x, wid = t >> 6, lane = t & 63;
    int wr = wid >> 2, wc = wid & 3;           // 2 x 4 wave grid
    int rl = lane & 15, klane = lane >> 4;

    // staging: wave w, iter i in {0,1}: rows [w*32+i*16, +16); lane -> row
    // +(l>>2), phys slot l&3; source slot = (l&3) ^ ((l>>3)&3) (row-derived,
    // wave/iter-independent since w*32, i*16 are ≡0 mod 4 after >>1)
    int slog = (lane & 3) ^ ((lane >> 3) & 3);
    size_t gs = (size_t)(wid * 32 + (lane >> 2)) * DIM + slog * 8;
    int ldst = (wid * 32) * KC;

    // fragment-read offsets: A rows wr*128 + f*16 + rl (f<8);
    //                        B rows wc*64  + g*16 + rl (g<4)
    int aoff[8], boff[4];
    #pragma unroll
    for (int f = 0; f < 8; ++f) {
        int ra = wr * 128 + f * 16 + rl;
        aoff[f] = ra * KC + ((klane ^ ((ra >> 1) & 3)) * 8);
    }
    #pragma unroll
    for (int g = 0; g < 4; ++g) {
        int rb = wc * 64 + g * 16 + rl;
        boff[g] = rb * KC + ((klane ^ ((rb >> 1) & 3)) * 8);
    }

    float ng2 = (float)negg[0];               // negative
    float m2g = -2.0f * ng2;                  // positive
    f32x2 m2g2 = {m2g, m2g};

    double bsum = 0.0;

    #define STAGE(kc, b)                                                       \
        do {                                                                   \
            gl_lds16(Abase + gs + (kc) * KC,                                   \
                     &As[(b) * ABUF + ldst]);                                  \
            gl_lds16(Abase + gs + (size_t)16 * DIM + (kc) * KC,                \
                     &As[(b) * ABUF + ldst + 16 * KC]);                        \
            gl_lds16(Bbase + gs + (kc) * KC,                                   \
                     &Bs[(b) * ABUF + ldst]);                                  \
            gl_lds16(Bbase + gs + (size_t)16 * DIM + (kc) * KC,                \
                     &Bs[(b) * ABUF + ldst + 16 * KC]);                        \
        } while (0)

    for (int pi = 0; pi < 3; ++pi) {
        int p = bid * 3 + pi;                 // consecutive: A-tile L2 reuse
        int ti = 0, rem = p;
        while (rem >= NTT - ti) { rem -= NTT - ti; ++ti; }
        int tj = ti + rem;

        const unsigned short* Abase = G + (size_t)ti * TS * DIM;
        const unsigned short* Bbase = G + (size_t)tj * TS * DIM;

        const f32x4 zero4 = {0.f, 0.f, 0.f, 0.f};
        f32x4 acc[8][4];
        #pragma unroll
        for (int f = 0; f < 8; ++f)
            #pragma unroll
            for (int g = 0; g < 4; ++g) acc[f][g] = zero4;

        STAGE(0, 0);
        #pragma unroll
        for (int kc = 0; kc < NC; ++kc) {
            asm volatile("s_waitcnt vmcnt(0)" ::: "memory");  // my 4 loads done
            __builtin_amdgcn_s_barrier();                      // all staged
            __builtin_amdgcn_sched_barrier(0);
            if (kc + 1 < NC) STAGE(kc + 1, (kc + 1) & 1);

            const unsigned short* Ab = &As[(kc & 1) * ABUF];
            const unsigned short* Bb = &Bs[(kc & 1) * ABUF];
            short8 af[8], bfv[4];
            #pragma unroll
            for (int f = 0; f < 8; ++f) af[f]  = *(const short8*)&Ab[aoff[f]];
            #pragma unroll
            for (int g = 0; g < 4; ++g) bfv[g] = *(const short8*)&Bb[boff[g]];
            #pragma unroll
            for (int f = 0; f < 8; ++f)
                #pragma unroll
                for (int g = 0; g < 4; ++g)
                    acc[f][g] = __builtin_amdgcn_mfma_f32_16x16x32_bf16(
                        af[f], bfv[g], acc[f][g], 0, 0, 0);
        }

        // ---- epilogue: packed-f32 exp2-squaring chain ----
        // C/D layout (m89): col = lane&15, row = (lane>>4)*4 + reg
        int gi0 = ti * TS + wr * 128;
        int gj0 = tj * TS + wc * 64;

        float sqb4[4];
        #pragma unroll
        for (int g = 0; g < 4; ++g) sqb4[g] = sq[gj0 + g * 16 + rl] * ng2;

        f32x2 tsv = {0.f, 0.f};
        #pragma unroll
        for (int f = 0; f < 8; ++f) {
            int base = gi0 + f * 16 + klane * 4;
            f32x2 sa01 = {sq[base + 0] * ng2, sq[base + 1] * ng2};
            f32x2 sa23 = {sq[base + 2] * ng2, sq[base + 3] * ng2};
            #pragma unroll
            for (int g = 0; g < 4; ++g) {
                f32x2 sb = {sqb4[g], sqb4[g]};
                f32x2 x01 = {acc[f][g][0], acc[f][g][1]};
                f32x2 x23 = {acc[f][g][2], acc[f][g][3]};
                x01 = x01 * m2g2 + (sa01 + sb);   // v_pk_fma + v_pk_add
                x23 = x23 * m2g2 + (sa23 + sb);
                f32x2 e01, e23;
                e01.x = exp2f(x01.x); e01.y = exp2f(x01.y);
                e23.x = exp2f(x23.x); e23.y = exp2f(x23.y);
                f32x2 p01 = e01 * e01, q01 = p01 * p01,
                      r01 = q01 * q01, s01 = r01 * r01;
                f32x2 p23 = e23 * e23, q23 = p23 * p23,
                      r23 = q23 * q23, s23 = r23 * r23;
                tsv += ((e01 + p01) + (q01 + r01)) + s01;
                tsv += ((e23 + p23) + (q23 + r23)) + s23;
            }
        }
        float tsum = tsv.x + tsv.y;

        float w = ((ti < NTT / 2) == (tj < NTT / 2)) ? 1.f : -1.f;
        if (ti != tj) w *= 2.f;   // off-diagonal tiles count twice (symmetry)
        bsum += (double)(tsum * w);
    }
    #undef STAGE

    // block reduce (once per block)
    #pragma unroll
    for (int off = 32; off; off >>= 1) bsum += __shfl_down(bsum, off);
    if (lane == 0) wsum[wid] = bsum;
    __syncthreads();
    if (t == 0) {
        double s = 0.0;
        #pragma unroll
        for (int i = 0; i < 8; ++i) s += wsum[i];
        slots[bid] = s;   // plain store, written every launch
    }
}

// ---------- kernel E: finalize (reduce 176 slots) ----------
__global__ __launch_bounds__(256) void k_final(const double* __restrict__ slots,
                                               float* __restrict__ out) {
    __shared__ double red[256];
    int t = threadIdx.x;
    red[t] = (t < GRID_MMD) ? slots[t] : 0.0;
    __syncthreads();
    for (int off = 128; off; off >>= 1) {
        if (t < off) red[t] += red[t + off];
        __syncthreads();
    }
    if (t == 0)
        out[0] = (float)(red[0] / ((double)HALF * (double)HALF));
}

extern "C" void kernel_launch(void* const* d_in, const int* in_sizes, int n_in,
                              void* d_out, int out_size, void* d_ws, size_t ws_size,
                              hipStream_t stream) {
    const float* src = (const float*)d_in[0];
    const float* tgt = (const float*)d_in[1];
    float* out = (float*)d_out;

    double* slots     = (double*)((char*)d_ws + WS_SLOT_OFF);
    double* negg      = (double*)((char*)d_ws + WS_NEGG_OFF);
    double* sqpart    = (double*)((char*)d_ws + WS_SQPART_OFF);
    float*  cspart    = (float*)((char*)d_ws + WS_CSPART_OFF);
    float*  sq        = (float*)((char*)d_ws + WS_SQ_OFF);
    unsigned short* G = (unsigned short*)((char*)d_ws + WS_G_OFF);

    k_prep<<<PREPB, 256, 0, stream>>>(src, tgt, G, sq, cspart, sqpart);
    k_bw<<<1, 256, 0, stream>>>(cspart, sqpart, negg);
    k_mmd<<<GRID_MMD, 512, 0, stream>>>(G, sq, negg, slots);
    k_final<<<1, 256, 0, stream>>>(slots, out);
}